// Round 1
// baseline (1223.859 us; speedup 1.0000x reference)
//
#include <hip/hip_runtime.h>
#include <math.h>

#define BB 4
#define LSEQ 2048
#define DMODEL 128
#define DINNER 256
#define DSTATE 16
#define DTRANK 8
#define NLAYERS 8
#define NCH 64     // number of time chunks
#define LCH 32     // chunk length (LSEQ / NCH)

__device__ __forceinline__ float silu_f(float x) {
    return x / (1.0f + __expf(-x));
}

__device__ __forceinline__ float softplus_f(float x) {
    return (x > 20.0f) ? x : log1pf(__expf(x));
}

// ---------------- stem: h[b,l,m] = sum_s x[b, l*4+s] * sw[m,s] + sb[m] ----
__global__ __launch_bounds__(256)
void k_stem(const float* __restrict__ x, const float* __restrict__ sw,
            const float* __restrict__ sb, float* __restrict__ h)
{
    int i = blockIdx.x * 256 + threadIdx.x;
    if (i >= BB * LSEQ * DMODEL) return;
    int m = i & (DMODEL - 1);
    int bl = i >> 7;           // b*LSEQ + l
    const float* xf = x + bl * 4;
    float4 w = *(const float4*)(sw + m * 4);
    h[i] = sb[m] + xf[0]*w.x + xf[1]*w.y + xf[2]*w.z + xf[3]*w.w;
}

// ---------------- K1: LayerNorm + in_proj (512 outputs) -------------------
// 16 positions per block, 256 threads. thread t computes outputs t (->xp_pre)
// and t+256 (->z) for all 16 positions.
__global__ __launch_bounds__(256)
void k_ln_inproj(const float* __restrict__ h, const float* __restrict__ g,
                 const float* __restrict__ bln, const float* __restrict__ W,
                 float* __restrict__ xp_pre, float* __restrict__ z)
{
    __shared__ float xn[16][DMODEL];
    int pos0 = blockIdx.x * 16;
    int t = threadIdx.x;
    for (int j = t; j < 16 * DMODEL; j += 256)
        xn[j >> 7][j & 127] = h[pos0 * DMODEL + j];
    __syncthreads();
    {
        // 16 rows, 16 threads per row; two-pass mean/var (matches jnp.var)
        int r = t >> 4, lane = t & 15;
        float s = 0.f;
        #pragma unroll
        for (int k = lane; k < DMODEL; k += 16) s += xn[r][k];
        #pragma unroll
        for (int off = 8; off > 0; off >>= 1) s += __shfl_xor(s, off, 16);
        float mu = s * (1.f / DMODEL);
        float vs = 0.f;
        #pragma unroll
        for (int k = lane; k < DMODEL; k += 16) { float dv = xn[r][k] - mu; vs += dv * dv; }
        #pragma unroll
        for (int off = 8; off > 0; off >>= 1) vs += __shfl_xor(vs, off, 16);
        float rstd = rsqrtf(vs * (1.f / DMODEL) + 1e-5f);
        #pragma unroll
        for (int k = lane; k < DMODEL; k += 16)
            xn[r][k] = (xn[r][k] - mu) * rstd * g[k] + bln[k];
    }
    __syncthreads();
    float acc0[16], acc1[16];
    #pragma unroll
    for (int p = 0; p < 16; p++) { acc0[p] = 0.f; acc1[p] = 0.f; }
    const float4* w0 = (const float4*)(W + t * DMODEL);
    const float4* w1 = (const float4*)(W + (t + DINNER) * DMODEL);
    for (int k4 = 0; k4 < DMODEL / 4; k4++) {
        float4 a = w0[k4], bq = w1[k4];
        #pragma unroll
        for (int p = 0; p < 16; p++) {
            float4 xv = *(const float4*)&xn[p][k4 * 4];
            acc0[p] += a.x*xv.x + a.y*xv.y + a.z*xv.z + a.w*xv.w;
            acc1[p] += bq.x*xv.x + bq.y*xv.y + bq.z*xv.z + bq.w*xv.w;
        }
    }
    #pragma unroll
    for (int p = 0; p < 16; p++) {
        xp_pre[(pos0 + p) * DINNER + t] = acc0[p];
        z[(pos0 + p) * DINNER + t]      = acc1[p];
    }
}

// ---------------- K2: causal dwconv + SiLU + x_proj + dt_proj + softplus --
__global__ __launch_bounds__(256)
void k_conv_xproj(const float* __restrict__ xp_pre, const float* __restrict__ cw,
                  const float* __restrict__ cb, const float* __restrict__ xw,
                  const float* __restrict__ dw, const float* __restrict__ db,
                  float* __restrict__ u, float* __restrict__ delta,
                  float* __restrict__ Bm, float* __restrict__ Cm)
{
    __shared__ float pre[19][DINNER];   // rows l0-3 .. l0+15
    __shared__ float xs[16][DINNER];
    __shared__ float dbl[16][40];
    int pos0 = blockIdx.x * 16;
    int l0 = pos0 & (LSEQ - 1);
    int t = threadIdx.x;
    for (int j = t; j < 19 * DINNER; j += 256) {
        int r = j >> 8, dd = j & 255;
        int l = l0 + r - 3;
        pre[r][dd] = (l < 0) ? 0.f : xp_pre[(pos0 - l0 + l) * DINNER + dd];
    }
    __syncthreads();
    {   // conv + silu; thread t = channel d
        int d = t;
        float4 cwv = *(const float4*)(cw + d * 4);
        float cbv = cb[d];
        #pragma unroll
        for (int p = 0; p < 16; p++) {
            float xc = cbv + pre[p][d]*cwv.x + pre[p+1][d]*cwv.y
                           + pre[p+2][d]*cwv.z + pre[p+3][d]*cwv.w;
            float v = silu_f(xc);
            xs[p][d] = v;
            u[(pos0 + p) * DINNER + d] = v;
        }
    }
    __syncthreads();
    for (int task = t; task < 16 * 40; task += 256) {
        int p = task / 40, o = task % 40;
        const float4* wr = (const float4*)(xw + o * DINNER);
        float acc = 0.f;
        for (int k4 = 0; k4 < DINNER / 4; k4++) {
            float4 wv = wr[k4];
            float4 xv = *(const float4*)&xs[p][k4 * 4];
            acc += wv.x*xv.x + wv.y*xv.y + wv.z*xv.z + wv.w*xv.w;
        }
        dbl[p][o] = acc;
    }
    __syncthreads();
    {   // delta = softplus(dt @ dw.T + db)
        int d = t;
        float4 dw0 = *(const float4*)(dw + d * 8);
        float4 dw1 = *(const float4*)(dw + d * 8 + 4);
        float dbv = db[d];
        #pragma unroll
        for (int p = 0; p < 16; p++) {
            float v = dbv
                + dbl[p][0]*dw0.x + dbl[p][1]*dw0.y + dbl[p][2]*dw0.z + dbl[p][3]*dw0.w
                + dbl[p][4]*dw1.x + dbl[p][5]*dw1.y + dbl[p][6]*dw1.z + dbl[p][7]*dw1.w;
            delta[(pos0 + p) * DINNER + d] = softplus_f(v);
        }
    }
    for (int task = t; task < 16 * 32; task += 256) {
        int p = task >> 5, j = task & 31;
        float v = dbl[p][8 + j];
        if (j < 16) Bm[(pos0 + p) * DSTATE + j] = v;
        else        Cm[(pos0 + p) * DSTATE + (j - 16)] = v;
    }
}

// ---------------- K3: local chunk scan (h starts at 0) --------------------
// grid (NCH, BB), 256 threads, thread = channel d; 16 states in registers.
__global__ __launch_bounds__(256)
void k_scanA(const float* __restrict__ delta, const float* __restrict__ u,
             const float* __restrict__ Bm, const float* __restrict__ Cm,
             const float* __restrict__ A_log, const float* __restrict__ Dv,
             float* __restrict__ y, float* __restrict__ P, float* __restrict__ hF)
{
    __shared__ float Bs[LCH][DSTATE];
    __shared__ float Cs[LCH][DSTATE];
    int c = blockIdx.x, b = blockIdx.y;
    int d = threadIdx.x;
    int t0 = c * LCH;
    for (int j = threadIdx.x; j < LCH * DSTATE; j += 256) {
        int tt = j >> 4, n = j & 15;
        Bs[tt][n] = Bm[(b * LSEQ + t0 + tt) * DSTATE + n];
        Cs[tt][n] = Cm[(b * LSEQ + t0 + tt) * DSTATE + n];
    }
    float Ar[DSTATE];
    #pragma unroll
    for (int n = 0; n < DSTATE; n++) Ar[n] = -__expf(A_log[d * DSTATE + n]);
    float Dd = Dv[d];
    float hs[DSTATE], S[DSTATE];
    #pragma unroll
    for (int n = 0; n < DSTATE; n++) { hs[n] = 0.f; S[n] = 0.f; }
    __syncthreads();
    const float* dp = delta + (b * LSEQ + t0) * DINNER + d;
    const float* up = u     + (b * LSEQ + t0) * DINNER + d;
    float* yp       = y     + (b * LSEQ + t0) * DINNER + d;
    for (int tt = 0; tt < LCH; tt++) {
        float dlt = dp[tt * DINNER];
        float uu  = up[tt * DINNER];
        float du  = dlt * uu;
        float acc = uu * Dd;
        #pragma unroll
        for (int n = 0; n < DSTATE; n++) {
            float xx = dlt * Ar[n];
            S[n] += xx;
            float a = __expf(xx);
            hs[n] = fmaf(a, hs[n], du * Bs[tt][n]);
            acc = fmaf(hs[n], Cs[tt][n], acc);
        }
        yp[tt * DINNER] = acc;
    }
    float* Pp = P  + ((b * NCH + c) * DINNER + d) * DSTATE;
    float* hp = hF + ((b * NCH + c) * DINNER + d) * DSTATE;
    #pragma unroll
    for (int n = 0; n < DSTATE; n++) { Pp[n] = __expf(S[n]); hp[n] = hs[n]; }
}

// ---------------- K4: sequential combine over chunks ----------------------
__global__ __launch_bounds__(256)
void k_scanB(const float* __restrict__ P, const float* __restrict__ hF,
             float* __restrict__ hin)
{
    int idx = blockIdx.x * 256 + threadIdx.x;   // over [b][d*16+n]
    if (idx >= BB * DINNER * DSTATE) return;
    int b = idx / (DINNER * DSTATE);
    int rem = idx % (DINNER * DSTATE);
    float hcur = 0.f;
    for (int c = 0; c < NCH; c++) {
        int a = (b * NCH + c) * (DINNER * DSTATE) + rem;
        hin[a] = hcur;
        hcur = P[a] * hcur + hF[a];
    }
}

// ---------------- K5: correction + gate + out_proj + residual -------------
__global__ __launch_bounds__(256)
void k_scanC_out(const float* __restrict__ delta, const float* __restrict__ Cm,
                 const float* __restrict__ A_log, const float* __restrict__ hin,
                 const float* __restrict__ y, const float* __restrict__ z,
                 const float* __restrict__ Wout, float* __restrict__ h)
{
    __shared__ float Cs[LCH][DSTATE];
    __shared__ float yg[LCH][DINNER];   // gated y for out_proj
    int c = blockIdx.x, b = blockIdx.y;
    int d = threadIdx.x;
    int t0 = c * LCH;
    for (int j = threadIdx.x; j < LCH * DSTATE; j += 256) {
        int tt = j >> 4, n = j & 15;
        Cs[tt][n] = Cm[(b * LSEQ + t0 + tt) * DSTATE + n];
    }
    float Ar[DSTATE], w[DSTATE];
    #pragma unroll
    for (int n = 0; n < DSTATE; n++) Ar[n] = -__expf(A_log[d * DSTATE + n]);
    const float* hp = hin + ((b * NCH + c) * DINNER + d) * DSTATE;
    #pragma unroll
    for (int n = 0; n < DSTATE; n++) w[n] = hp[n];
    __syncthreads();
    const float* dp  = delta + (b * LSEQ + t0) * DINNER + d;
    const float* ypl = y     + (b * LSEQ + t0) * DINNER + d;
    const float* zp  = z     + (b * LSEQ + t0) * DINNER + d;
    for (int tt = 0; tt < LCH; tt++) {
        float dlt = dp[tt * DINNER];
        float corr = 0.f;
        #pragma unroll
        for (int n = 0; n < DSTATE; n++) {
            w[n] *= __expf(dlt * Ar[n]);
            corr = fmaf(w[n], Cs[tt][n], corr);
        }
        float yv = ypl[tt * DINNER] + corr;
        float zv = zp[tt * DINNER];
        yg[tt][d] = yv * silu_f(zv);
    }
    __syncthreads();
    // out_proj: thread (m = d&127, podd = d>>7) computes 16 positions p=2i+podd
    int m = d & 127, podd = d >> 7;
    float acc[16];
    #pragma unroll
    for (int i = 0; i < 16; i++) acc[i] = 0.f;
    const float4* wr = (const float4*)(Wout + m * DINNER);
    for (int k4 = 0; k4 < DINNER / 4; k4++) {
        float4 wv = wr[k4];
        #pragma unroll
        for (int i = 0; i < 16; i++) {
            float4 yv = *(const float4*)&yg[2 * i + podd][k4 * 4];
            acc[i] += wv.x*yv.x + wv.y*yv.y + wv.z*yv.z + wv.w*yv.w;
        }
    }
    #pragma unroll
    for (int i = 0; i < 16; i++) {
        int gi = (b * LSEQ + t0 + 2 * i + podd) * DMODEL + m;
        h[gi] += acc[i];   // residual, in-place (each element owned by 1 thread)
    }
}

// ---------------- head: mean-pool + classifier ---------------------------
__global__ __launch_bounds__(256)
void k_head(const float* __restrict__ h, const float* __restrict__ hw,
            const float* __restrict__ hb, float* __restrict__ out)
{
    __shared__ float part[256];
    __shared__ float pool[DMODEL];
    int b = blockIdx.x;
    int t = threadIdx.x;
    int m = t & 127, half = t >> 7;
    float s = 0.f;
    const float* hp = h + (b * LSEQ + half * (LSEQ / 2)) * DMODEL + m;
    for (int l = 0; l < LSEQ / 2; l++) s += hp[l * DMODEL];
    part[t] = s;
    __syncthreads();
    if (t < DMODEL) pool[t] = (part[t] + part[t + 128]) * (1.f / LSEQ);
    __syncthreads();
    if (t < 35) {
        const float* wr = hw + t * DMODEL;
        float acc = hb[t];
        for (int k = 0; k < DMODEL; k++) acc += pool[k] * wr[k];
        out[b * 35 + t] = acc;
    }
}

extern "C" void kernel_launch(void* const* d_in, const int* in_sizes, int n_in,
                              void* d_out, int out_size, void* d_ws, size_t ws_size,
                              hipStream_t stream)
{
    const float* x       = (const float*)d_in[0];
    const float* stem_w  = (const float*)d_in[1];
    const float* stem_b  = (const float*)d_in[2];
    const float* ln_g    = (const float*)d_in[3];
    const float* ln_b    = (const float*)d_in[4];
    const float* in_w    = (const float*)d_in[5];
    const float* conv_w  = (const float*)d_in[6];
    const float* conv_b  = (const float*)d_in[7];
    const float* xw      = (const float*)d_in[8];
    const float* dt_w    = (const float*)d_in[9];
    const float* dt_b    = (const float*)d_in[10];
    const float* A_log   = (const float*)d_in[11];
    const float* Dv      = (const float*)d_in[12];
    const float* out_w   = (const float*)d_in[13];
    const float* head_w  = (const float*)d_in[14];
    const float* head_b  = (const float*)d_in[15];
    float* out = (float*)d_out;

    // workspace layout (floats); total ~14.9M floats (~60 MB)
    float* ws     = (float*)d_ws;
    float* h      = ws;
    float* xp_pre = h      + (size_t)BB * LSEQ * DMODEL;
    float* zbuf   = xp_pre + (size_t)BB * LSEQ * DINNER;
    float* ubuf   = zbuf   + (size_t)BB * LSEQ * DINNER;
    float* dbuf   = ubuf   + (size_t)BB * LSEQ * DINNER;
    float* Bmb    = dbuf   + (size_t)BB * LSEQ * DINNER;
    float* Cmb    = Bmb    + (size_t)BB * LSEQ * DSTATE;
    float* ybuf   = Cmb    + (size_t)BB * LSEQ * DSTATE;
    float* Pb     = ybuf   + (size_t)BB * LSEQ * DINNER;
    float* hFb    = Pb     + (size_t)BB * NCH * DINNER * DSTATE;
    float* hinb   = hFb    + (size_t)BB * NCH * DINNER * DSTATE;

    k_stem<<<(BB * LSEQ * DMODEL + 255) / 256, 256, 0, stream>>>(x, stem_w, stem_b, h);

    dim3 gs(NCH, BB);
    for (int ly = 0; ly < NLAYERS; ly++) {
        k_ln_inproj<<<BB * LSEQ / 16, 256, 0, stream>>>(
            h, ln_g + ly * DMODEL, ln_b + ly * DMODEL,
            in_w + (size_t)ly * 2 * DINNER * DMODEL, xp_pre, zbuf);
        k_conv_xproj<<<BB * LSEQ / 16, 256, 0, stream>>>(
            xp_pre, conv_w + (size_t)ly * DINNER * 4, conv_b + (size_t)ly * DINNER,
            xw + (size_t)ly * 40 * DINNER, dt_w + (size_t)ly * DINNER * DTRANK,
            dt_b + (size_t)ly * DINNER, ubuf, dbuf, Bmb, Cmb);
        k_scanA<<<gs, 256, 0, stream>>>(
            dbuf, ubuf, Bmb, Cmb, A_log + (size_t)ly * DINNER * DSTATE,
            Dv + (size_t)ly * DINNER, ybuf, Pb, hFb);
        k_scanB<<<(BB * DINNER * DSTATE + 255) / 256, 256, 0, stream>>>(Pb, hFb, hinb);
        k_scanC_out<<<gs, 256, 0, stream>>>(
            dbuf, Cmb, A_log + (size_t)ly * DINNER * DSTATE, hinb,
            ybuf, zbuf, out_w + (size_t)ly * DMODEL * DINNER, h);
    }
    k_head<<<BB, 256, 0, stream>>>(h, head_w, head_b, out);
}